// Round 16
// baseline (78.793 us; speedup 1.0000x reference)
//
#include <hip/hip_runtime.h>

#define BB 4
#define NN 16384
#define MM 8192      // N/2
#define FD 64
#define TPB 256
#define QPT 4
#define QPB (TPB * QPT)   // 1024 queries per query-block

// d_out float offsets
#define OUT0 0              // valid_pc   (4,8192,3)
#define OUT1 98304          // valid_feats(4,8192,64)
#define OUT2 2195456        // n_idx      (4,8192)
#define OUT3 2228224        // rnds       (1,16384)

// d_ws layout
#define CAND_OFF   0
#define CAND_BYTES ((size_t)BB * MM * 16)                 // 512 KB
#define CPAIR_OFF  (CAND_OFF + CAND_BYTES)
#define CPAIR_BYTES ((size_t)BB * MM * 8)                 // 256 KB
#define PART_OFF   (CPAIR_OFF + CPAIR_BYTES)

// ---- HW-verified bit-exact pieces (r7/r10/r15: absmax 0) ----
__device__ __forceinline__ float sumsq3_rn(float x, float y, float z) {
  return __fadd_rn(__fadd_rn(__fmul_rn(x, x), __fmul_rn(y, y)), __fmul_rn(z, z));
}
__device__ __forceinline__ float dist2_rn(float qx, float qy, float qz, float q2,
                                          float4 t) {
  float cross2 = __fmaf_rn(qz, t.z, __fmaf_rn(qy, t.y, __fmul_rn(qx, t.x)));
  return __fadd_rn(__fsub_rn(q2, cross2), t.w);
}
__device__ __forceinline__ double mkkey(float d2, int k) {
  return __hiloint2double(__float_as_int(d2), k);
}
#define KEY_INIT __hiloint2double(0x7F800000, 0x7FFFFFFF)

// gather + cand prep (r9-proven)
__global__ __launch_bounds__(256) void gather_kernel(
    const float* __restrict__ pc, const float* __restrict__ feats,
    const int* __restrict__ perm, float* __restrict__ out,
    float4* __restrict__ cand) {
  int idx = blockIdx.x * 256 + threadIdx.x;
  const int F4_TOT = BB * MM * FD / 4;
  const int PTS    = BB * MM;
  if (idx < F4_TOT) {
    int f4 = idx & 15;
    int r  = (idx >> 4) & (MM - 1);
    int b  = idx >> 17;
    int vi = perm[r];
    const float4* src = (const float4*)(feats + ((b * NN + vi) << 6));
    float4* dst = (float4*)(out + OUT1) + idx;
    *dst = src[f4];
  } else if (idx < F4_TOT + PTS) {
    int k = idx - F4_TOT;
    int r = k & (MM - 1);
    int b = k >> 13;
    int vi = perm[r];
    const float* src = pc + (b * NN + vi) * 3;
    float px = src[0], py = src[1], pz = src[2];
    float* dst = out + OUT0 + k * 3;
    dst[0] = px; dst[1] = py; dst[2] = pz;
    cand[k] = make_float4(px + px, py + py, pz + pz, sumsq3_rn(px, py, pz));
  } else if (idx < F4_TOT + PTS + NN) {
    int k = idx - F4_TOT - PTS;
    out[OUT3 + k] = (float)perm[k];
  }
}

// Main pass: top-2 VALUES per (query, chunk). QPT=4 amortizes each ds_read_b128
// over 4 queries; body = 7 lean f32 ops/pair (r7/r15-proven recurrence).
__global__ __launch_bounds__(256) void knn_val_kernel(
    const float* __restrict__ pc, const int* __restrict__ perm,
    const float4* __restrict__ cand, float2* __restrict__ part, int nchunk) {
  #pragma clang fp contract(off)
  int c  = blockIdx.x % nchunk;
  int qb = blockIdx.x / nchunk;       // 0..31
  int q0 = qb * QPB + threadIdx.x;
  int b  = qb >> 3;                   // QPB=1024: 8 qblocks per batch

  float qx[QPT], qy[QPT], qz[QPT], q2[QPT], m1[QPT], m2[QPT];
  #pragma unroll
  for (int s = 0; s < QPT; ++s) {
    int q = q0 + s * TPB;
    int j = q & (MM - 1);
    int qi = perm[MM + j];
    const float* qp = pc + (b * NN + qi) * 3;
    qx[s] = qp[0]; qy[s] = qp[1]; qz[s] = qp[2];
    q2[s] = sumsq3_rn(qx[s], qy[s], qz[s]);
    m1[s] = 3.4e38f; m2[s] = 3.4e38f;
  }

  __shared__ float4 tile[256];        // up to 4 KB used (span <= 256)

  int span = MM / nchunk;             // 128 (nchunk=64) .. 1024 (nchunk=8)
  int begin = c * span, end = begin + span;

  for (int t0 = begin; t0 < end; t0 += 256) {
    int tlen = min(256, end - t0);
    __syncthreads();
    for (int i = threadIdx.x; i < tlen; i += TPB)
      tile[i] = cand[b * MM + t0 + i];
    __syncthreads();
    #pragma unroll 8
    for (int k = 0; k < tlen; ++k) {
      float4 t = tile[k];
      #pragma unroll
      for (int s = 0; s < QPT; ++s) {
        float d2 = dist2_rn(qx[s], qy[s], qz[s], q2[s], t);
        m2[s] = __builtin_amdgcn_fmed3f(d2, m1[s], m2[s]);
        m1[s] = fminf(d2, m1[s]);
      }
    }
  }

  #pragma unroll
  for (int s = 0; s < QPT; ++s) {
    int q = q0 + s * TPB;
    part[q * nchunk + c] = make_float2(m1[s], m2[s]);
  }
}

// Merge: per query, pack (value, chunk) as f64 keys (chunk order == index-range
// order, so earlier-chunk tie-wins == lower-index tie-wins, matching stable
// top_k — r10/r15-verified). Emits the two chunks holding the stable top-2.
__global__ __launch_bounds__(256) void merge_kernel(
    const float2* __restrict__ part, int2* __restrict__ cpair, int nchunk) {
  int q = blockIdx.x * 256 + threadIdx.x;
  double k1 = KEY_INIT, k2 = KEY_INIT;
  for (int c = 0; c < nchunk; ++c) {
    float2 p = part[q * nchunk + c];
    double a = mkkey(p.x, c);
    double d = mkkey(p.y, c);
    k2 = fmin(fmax(a, k1), k2);
    k1 = fmin(a, k1);
    k2 = fmin(fmax(d, k1), k2);
    k1 = fmin(d, k1);
  }
  cpair[q] = make_int2(__double2loint(k1), __double2loint(k2));
}

// Recovery: one wave per query; rescan chunks c1 (and c2 if distinct) with the
// exact f64 (d2,index) key machine (r10/r15-proven), lane-parallel + shfl.
__global__ __launch_bounds__(256) void recover_kernel(
    const float* __restrict__ pc, const int* __restrict__ perm,
    const float4* __restrict__ cand, const int2* __restrict__ cpair,
    float* __restrict__ out, int nchunk) {
  #pragma clang fp contract(off)
  int wid = threadIdx.x >> 6, lane = threadIdx.x & 63;
  int q = blockIdx.x * 4 + wid;       // 0..B*M-1
  int b = q >> 13, j = q & (MM - 1);
  int qi = perm[MM + j];
  const float* qp = pc + (b * NN + qi) * 3;   // wave-uniform loads
  float qx = qp[0], qy = qp[1], qz = qp[2];
  float q2 = sumsq3_rn(qx, qy, qz);
  int2 cp = cpair[q];
  int clen = MM / nchunk;
  const float4* cb = cand + (b << 13);

  double m1 = KEY_INIT, m2 = KEY_INIT;
  #pragma unroll
  for (int pass = 0; pass < 2; ++pass) {
    int c = pass == 0 ? cp.x : cp.y;
    if (pass == 1 && cp.y == cp.x) break;   // no double-insertion
    int base = c * clen;
    for (int i = lane; i < clen; i += 64) { // coalesced
      float4 t = cb[base + i];
      float d2 = dist2_rn(qx, qy, qz, q2, t);
      double key = mkkey(d2, base + i);
      m2 = fmin(fmax(key, m1), m2);
      m1 = fmin(key, m1);
    }
  }
  #pragma unroll
  for (int mask = 1; mask < 64; mask <<= 1) {
    double o1 = __shfl_xor(m1, mask);
    double o2 = __shfl_xor(m2, mask);
    double n1 = fmin(m1, o1);
    double n2 = fmin(fmax(m1, o1), fmin(m2, o2));
    m1 = n1; m2 = n2;
  }
  if (lane == 0) out[OUT2 + q] = (float)__double2loint(m2);
}

extern "C" void kernel_launch(void* const* d_in, const int* in_sizes, int n_in,
                              void* d_out, int out_size, void* d_ws, size_t ws_size,
                              hipStream_t stream) {
  const float* pc    = (const float*)d_in[0];
  const float* feats = (const float*)d_in[1];
  const int*   perm  = (const int*)d_in[2];
  float* out = (float*)d_out;

  char* ws = (char*)d_ws;
  float4* cand  = (float4*)(ws + CAND_OFF);
  int2*   cpair = (int2*)(ws + CPAIR_OFF);
  float2* part  = (float2*)(ws + PART_OFF);
  size_t  avail = ws_size > PART_OFF ? ws_size - PART_OFF : 0;

  gather_kernel<<<2240, 256, 0, stream>>>(pc, feats, perm, out, cand);

  // qblocks = 32 (QPT=4): nchunk=64 -> 2048 blocks (8/CU, 32 waves/CU).
  int nchunk = 8;
  if      (avail >= (size_t)BB * MM * 64 * sizeof(float2)) nchunk = 64;  // 16.8 MB
  else if (avail >= (size_t)BB * MM * 32 * sizeof(float2)) nchunk = 32;
  else if (avail >= (size_t)BB * MM * 16 * sizeof(float2)) nchunk = 16;

  knn_val_kernel<<<(BB * MM / QPB) * nchunk, TPB, 0, stream>>>(pc, perm, cand,
                                                               part, nchunk);
  merge_kernel<<<BB * MM / 256, 256, 0, stream>>>(part, cpair, nchunk);
  recover_kernel<<<BB * MM / 4, 256, 0, stream>>>(pc, perm, cand, cpair, out, nchunk);
}

// Round 17
// 76.945 us; speedup vs baseline: 1.0240x; 1.0240x over previous
//
#include <hip/hip_runtime.h>

typedef float v2f __attribute__((ext_vector_type(2)));
typedef float v4f __attribute__((ext_vector_type(4)));

#define BB 4
#define NN 16384
#define MM 8192      // N/2
#define FD 64
#define TPB 256
#define QPT 4
#define QPB (TPB * QPT)   // 1024 queries per query-block

// d_out float offsets
#define OUT0 0              // valid_pc   (4,8192,3)
#define OUT1 98304          // valid_feats(4,8192,64)
#define OUT2 2195456        // n_idx      (4,8192)
#define OUT3 2228224        // rnds       (1,16384)

// d_ws layout
#define CAND_OFF   0
#define CAND_BYTES ((size_t)BB * MM * 16)                 // 512 KB
#define PART_OFF   CAND_BYTES

// ---- HW-verified bit-exact pieces (r7/r10/r15: absmax 0) ----
__device__ __forceinline__ float sumsq3_rn(float x, float y, float z) {
  return __fadd_rn(__fadd_rn(__fmul_rn(x, x), __fmul_rn(y, y)), __fmul_rn(z, z));
}
__device__ __forceinline__ float dist2_rn(float qx, float qy, float qz, float q2,
                                          float4 t) {
  float cross2 = __fmaf_rn(qz, t.z, __fmaf_rn(qy, t.y, __fmul_rn(qx, t.x)));
  return __fadd_rn(__fsub_rn(q2, cross2), t.w);
}
__device__ __forceinline__ double mkkey(float d2, int k) {
  return __hiloint2double(__float_as_int(d2), k);
}
#define KEY_INIT __hiloint2double(0x7F800000, 0x7FFFFFFF)

// gather + cand prep (r9-proven)
__global__ __launch_bounds__(256) void gather_kernel(
    const float* __restrict__ pc, const float* __restrict__ feats,
    const int* __restrict__ perm, float* __restrict__ out,
    float4* __restrict__ cand) {
  int idx = blockIdx.x * 256 + threadIdx.x;
  const int F4_TOT = BB * MM * FD / 4;
  const int PTS    = BB * MM;
  if (idx < F4_TOT) {
    int f4 = idx & 15;
    int r  = (idx >> 4) & (MM - 1);
    int b  = idx >> 17;
    int vi = perm[r];
    const float4* src = (const float4*)(feats + ((b * NN + vi) << 6));
    float4* dst = (float4*)(out + OUT1) + idx;
    *dst = src[f4];
  } else if (idx < F4_TOT + PTS) {
    int k = idx - F4_TOT;
    int r = k & (MM - 1);
    int b = k >> 13;
    int vi = perm[r];
    const float* src = pc + (b * NN + vi) * 3;
    float px = src[0], py = src[1], pz = src[2];
    float* dst = out + OUT0 + k * 3;
    dst[0] = px; dst[1] = py; dst[2] = pz;
    cand[k] = make_float4(px + px, py + py, pz + pz, sumsq3_rn(px, py, pz));
  } else if (idx < F4_TOT + PTS + NN) {
    int k = idx - F4_TOT - PTS;
    out[OUT3 + k] = (float)perm[k];
  }
}

// Main pass: top-2 VALUES per (query, chunk). SoA LDS tile + packed-f32 math
// (v_pk_mul/fma/add are per-element IEEE rn == the verified scalar chain);
// med3/min update is order-independent over values (no indices).
__global__ __launch_bounds__(256) void knn_val_kernel(
    const float* __restrict__ pc, const int* __restrict__ perm,
    const float4* __restrict__ cand, float2* __restrict__ part, int nchunk) {
  #pragma clang fp contract(off)
  int c  = blockIdx.x % nchunk;
  int qb = blockIdx.x / nchunk;       // 0..31
  int q0 = qb * QPB + threadIdx.x;
  int b  = qb >> 3;                   // QPB=1024: 8 qblocks per batch

  float m1[QPT], m2[QPT];
  v2f qxp[QPT], qyp[QPT], qzp[QPT], q2p[QPT];
  #pragma unroll
  for (int s = 0; s < QPT; ++s) {
    int q = q0 + s * TPB;
    int j = q & (MM - 1);
    int qi = perm[MM + j];
    const float* qp = pc + (b * NN + qi) * 3;
    float qx = qp[0], qy = qp[1], qz = qp[2];
    float q2 = sumsq3_rn(qx, qy, qz);
    qxp[s] = (v2f){qx, qx}; qyp[s] = (v2f){qy, qy};
    qzp[s] = (v2f){qz, qz}; q2p[s] = (v2f){q2, q2};
    m1[s] = 3.4e38f; m2[s] = 3.4e38f;
  }

  __shared__ __align__(16) float lx[256], ly[256], lz[256], lw[256];  // SoA 4KB

  int span = MM / nchunk;             // 128..1024, multiple of 128
  int begin = c * span, end = begin + span;

  for (int t0 = begin; t0 < end; t0 += 256) {
    int tlen = min(256, end - t0);
    __syncthreads();
    if (threadIdx.x < tlen) {
      float4 t = cand[b * MM + t0 + threadIdx.x];
      lx[threadIdx.x] = t.x; ly[threadIdx.x] = t.y;
      lz[threadIdx.x] = t.z; lw[threadIdx.x] = t.w;
    }
    __syncthreads();
    #pragma unroll 2
    for (int k = 0; k < tlen; k += 4) {
      v4f x4 = *(const v4f*)&lx[k];
      v4f y4 = *(const v4f*)&ly[k];
      v4f z4 = *(const v4f*)&lz[k];
      v4f w4 = *(const v4f*)&lw[k];
      v2f xa = __builtin_shufflevector(x4, x4, 0, 1);
      v2f xb = __builtin_shufflevector(x4, x4, 2, 3);
      v2f ya = __builtin_shufflevector(y4, y4, 0, 1);
      v2f yb = __builtin_shufflevector(y4, y4, 2, 3);
      v2f za = __builtin_shufflevector(z4, z4, 0, 1);
      v2f zb = __builtin_shufflevector(z4, z4, 2, 3);
      v2f wa = __builtin_shufflevector(w4, w4, 0, 1);
      v2f wb = __builtin_shufflevector(w4, w4, 2, 3);
      #pragma unroll
      for (int s = 0; s < QPT; ++s) {
        // per element: rn(rn(q2 - fma(qz,2pz,fma(qy,2py,rn(qx*2px)))) + p2)
        v2f crA = __builtin_elementwise_fma(qzp[s], za,
                  __builtin_elementwise_fma(qyp[s], ya, qxp[s] * xa));
        v2f dA  = (q2p[s] - crA) + wa;
        m2[s] = __builtin_amdgcn_fmed3f(dA.x, m1[s], m2[s]);
        m1[s] = fminf(dA.x, m1[s]);
        m2[s] = __builtin_amdgcn_fmed3f(dA.y, m1[s], m2[s]);
        m1[s] = fminf(dA.y, m1[s]);
        v2f crB = __builtin_elementwise_fma(qzp[s], zb,
                  __builtin_elementwise_fma(qyp[s], yb, qxp[s] * xb));
        v2f dB  = (q2p[s] - crB) + wb;
        m2[s] = __builtin_amdgcn_fmed3f(dB.x, m1[s], m2[s]);
        m1[s] = fminf(dB.x, m1[s]);
        m2[s] = __builtin_amdgcn_fmed3f(dB.y, m1[s], m2[s]);
        m1[s] = fminf(dB.y, m1[s]);
      }
    }
  }

  #pragma unroll
  for (int s = 0; s < QPT; ++s) {
    int q = q0 + s * TPB;
    part[q * nchunk + c] = make_float2(m1[s], m2[s]);
  }
}

// Fused merge+recover: one wave per query. Lane c packs (value, chunk) keys
// (chunk order == index-range order -> stable tie semantics, r15-verified),
// shfl-xor top-2 merge picks the <=2 chunks holding the stable top-2, then
// rescan those chunks with the exact f64 (d2,index) key machine (r10-proven).
__global__ __launch_bounds__(256) void recover_kernel(
    const float* __restrict__ pc, const int* __restrict__ perm,
    const float4* __restrict__ cand, const float2* __restrict__ part,
    float* __restrict__ out, int nchunk) {
  #pragma clang fp contract(off)
  int wid = threadIdx.x >> 6, lane = threadIdx.x & 63;
  int q = blockIdx.x * 4 + wid;       // 0..B*M-1
  int b = q >> 13, j = q & (MM - 1);
  int qi = perm[MM + j];
  const float* qp = pc + (b * NN + qi) * 3;   // wave-uniform loads
  float qx = qp[0], qy = qp[1], qz = qp[2];
  float q2 = sumsq3_rn(qx, qy, qz);

  // merge phase: lane c holds chunk c's (m1,m2) as keys (m1<=m2 per chunk)
  double k1 = KEY_INIT, k2 = KEY_INIT;
  if (lane < nchunk) {
    float2 p = part[q * nchunk + lane];
    k1 = mkkey(p.x, lane);
    k2 = mkkey(p.y, lane);
  }
  #pragma unroll
  for (int mask = 1; mask < 64; mask <<= 1) {
    double o1 = __shfl_xor(k1, mask);
    double o2 = __shfl_xor(k2, mask);
    double n1 = fmin(k1, o1);
    double n2 = fmin(fmax(k1, o1), fmin(k2, o2));
    k1 = n1; k2 = n2;
  }
  int c1 = __double2loint(k1);        // all lanes converged
  int c2 = __double2loint(k2);

  int clen = MM / nchunk;
  const float4* cb = cand + (b << 13);
  double m1 = KEY_INIT, m2 = KEY_INIT;
  #pragma unroll
  for (int pass = 0; pass < 2; ++pass) {
    int c = pass == 0 ? c1 : c2;
    if (pass == 1 && c2 == c1) break;   // no double-insertion
    int base = c * clen;
    for (int i = lane; i < clen; i += 64) {   // coalesced
      float4 t = cb[base + i];
      float d2 = dist2_rn(qx, qy, qz, q2, t);
      double key = mkkey(d2, base + i);
      m2 = fmin(fmax(key, m1), m2);
      m1 = fmin(key, m1);
    }
  }
  #pragma unroll
  for (int mask = 1; mask < 64; mask <<= 1) {
    double o1 = __shfl_xor(m1, mask);
    double o2 = __shfl_xor(m2, mask);
    double n1 = fmin(m1, o1);
    double n2 = fmin(fmax(m1, o1), fmin(m2, o2));
    m1 = n1; m2 = n2;
  }
  if (lane == 0) out[OUT2 + q] = (float)__double2loint(m2);
}

extern "C" void kernel_launch(void* const* d_in, const int* in_sizes, int n_in,
                              void* d_out, int out_size, void* d_ws, size_t ws_size,
                              hipStream_t stream) {
  const float* pc    = (const float*)d_in[0];
  const float* feats = (const float*)d_in[1];
  const int*   perm  = (const int*)d_in[2];
  float* out = (float*)d_out;

  char* ws = (char*)d_ws;
  float4* cand = (float4*)(ws + CAND_OFF);
  float2* part = (float2*)(ws + PART_OFF);
  size_t  avail = ws_size > PART_OFF ? ws_size - PART_OFF : 0;

  gather_kernel<<<2240, 256, 0, stream>>>(pc, feats, perm, out, cand);

  // qblocks = 32 (QPT=4): nchunk=64 -> 2048 blocks (8/CU, 32 waves/CU).
  int nchunk = 8;
  if      (avail >= (size_t)BB * MM * 64 * sizeof(float2)) nchunk = 64;  // 16.8 MB
  else if (avail >= (size_t)BB * MM * 32 * sizeof(float2)) nchunk = 32;
  else if (avail >= (size_t)BB * MM * 16 * sizeof(float2)) nchunk = 16;

  knn_val_kernel<<<(BB * MM / QPB) * nchunk, TPB, 0, stream>>>(pc, perm, cand,
                                                               part, nchunk);
  recover_kernel<<<BB * MM / 4, 256, 0, stream>>>(pc, perm, cand, part, out, nchunk);
}